// Round 1
// baseline (1216.063 us; speedup 1.0000x reference)
//
#include <hip/hip_runtime.h>
#include <math.h>

// Problem constants (match reference)
#define BB    2
#define NN    2048
#define HSZ   1024
#define NH    16
#define HD    64
#define SEGW  20     // rope segment width (3 segments + 4 passthrough dims)

// ---------------------------------------------------------------------------
// RoPE cos/sin table: tab[n][d][2] = {cos, sin} for flat head-dim index d.
// Faithful to reference: sin/cos are TILED -> index d within a 20-wide segment
// uses omega_{(d%20) % 10}; dims 60..63 passthrough => (c,s)=(1,0) makes the
// pairwise rotation an identity (branch-free epilogue).
// ---------------------------------------------------------------------------
__global__ void rope_table_k(float* __restrict__ tab) {
    int n = blockIdx.x;     // 0..2047
    int d = threadIdx.x;    // 0..63
    float c = 1.f, s = 0.f;
    if (d < 3 * SEGW) {
        int seg = d / SEGW;
        int jj  = (d % SEGW) % (SEGW / 2);      // 0..9
        int rem = n & 255;                      // tokens-per-frame = 16*16
        int pos = (seg == 0) ? (n >> 8) : ((seg == 1) ? (rem >> 4) : (rem & 15));
        float omega = powf(10000.f, -(float)jj / 10.f);
        float fr = (float)pos * omega;
        s = sinf(fr);
        c = cosf(fr);
    }
    tab[(n * 64 + d) * 2 + 0] = c;
    tab[(n * 64 + d) * 2 + 1] = s;
}

// ---------------------------------------------------------------------------
// Tiled fp32 GEMM:  C[m,o] = sum_k X[m,k] * W[o,k]  + bias[o]
//   X: [M=4096, 1024] row-major, W: [1024,1024] row-major (we use W^T product)
// mode 0/1: rope epilogue, write to head layout [b][h][n][d]
// mode 2  : plain,        write to head layout
// mode 3  : plain,        write row-major [m][o] (final output)
// Block: 256 threads, 64x64 tile, 4x4 per thread, K-step 16.
// LDS transposed [k][m] so inner loop is 2x ds_read_b128 + 16 FMA per k.
// ---------------------------------------------------------------------------
__global__ __launch_bounds__(256)
void proj_k(const float* __restrict__ X, const float* __restrict__ W,
            const float* __restrict__ bias, float* __restrict__ out,
            const float* __restrict__ tab, int mode) {
    __shared__ float Xs[16][68];   // [k][m], pad 68: bank = (4k+m)%32, 16B aligned
    __shared__ float Ws[16][68];   // [k][o]

    const int t  = threadIdx.x;
    const int tx = t & 15;         // o-direction (4 cols each)
    const int ty = t >> 4;         // m-direction (4 rows each)
    const int o0 = blockIdx.x * 64;
    const int m0 = blockIdx.y * 64;
    const int ml = t >> 2;         // staging row 0..63
    const int kq = t & 3;          // staging k-quad 0..3

    float acc[4][4] = {};

    for (int k0 = 0; k0 < HSZ; k0 += 16) {
        float4 xa = *(const float4*)(X + (size_t)(m0 + ml) * HSZ + k0 + kq * 4);
        float4 wa = *(const float4*)(W + (size_t)(o0 + ml) * HSZ + k0 + kq * 4);
        __syncthreads();           // previous iter's reads complete
        Xs[kq * 4 + 0][ml] = xa.x;
        Xs[kq * 4 + 1][ml] = xa.y;
        Xs[kq * 4 + 2][ml] = xa.z;
        Xs[kq * 4 + 3][ml] = xa.w;
        Ws[kq * 4 + 0][ml] = wa.x;
        Ws[kq * 4 + 1][ml] = wa.y;
        Ws[kq * 4 + 2][ml] = wa.z;
        Ws[kq * 4 + 3][ml] = wa.w;
        __syncthreads();
#pragma unroll
        for (int kk = 0; kk < 16; ++kk) {
            float4 av = *(const float4*)&Xs[kk][ty * 4];
            float4 bv = *(const float4*)&Ws[kk][tx * 4];
            float a_[4] = {av.x, av.y, av.z, av.w};
            float b_[4] = {bv.x, bv.y, bv.z, bv.w};
#pragma unroll
            for (int i = 0; i < 4; ++i)
#pragma unroll
                for (int j = 0; j < 4; ++j)
                    acc[i][j] = fmaf(a_[i], b_[j], acc[i][j]);
        }
    }

    // Epilogue: bias (+rope) (+layout transform)
    float4 bvec = *(const float4*)(bias + o0 + tx * 4);
#pragma unroll
    for (int i = 0; i < 4; ++i) {
        int m  = m0 + ty * 4 + i;
        int nn = m & (NN - 1);
        float v0 = acc[i][0] + bvec.x;
        float v1 = acc[i][1] + bvec.y;
        float v2 = acc[i][2] + bvec.z;
        float v3 = acc[i][3] + bvec.w;
        if (mode <= 1) {
            // rope pairs (d0,d0+1),(d0+2,d0+3); d0 = tx*4 (even, within one segment)
            // tab gives {c,s} per flat dim; pair uses DIFFERENT omegas (tiled sin/cos)
            float4 cs0 = *(const float4*)(tab + ((size_t)nn * 64 + tx * 4 + 0) * 2); // c0,s0,c1,s1
            float4 cs1 = *(const float4*)(tab + ((size_t)nn * 64 + tx * 4 + 2) * 2); // c2,s2,c3,s3
            float x0 = v0, x1 = v1, x2 = v2, x3 = v3;
            v0 = x0 * cs0.x - x1 * cs0.y;
            v1 = x1 * cs0.z + x0 * cs0.w;
            v2 = x2 * cs1.x - x3 * cs1.y;
            v3 = x3 * cs1.z + x2 * cs1.w;
        }
        float4 r = {v0, v1, v2, v3};
        if (mode < 3) {
            int b_ = m >> 11;          // m / NN
            int h_ = o0 >> 6;          // 64-wide o-tile == exactly one head
            *(float4*)(out + (((size_t)b_ * NH + h_) * NN + nn) * HD + tx * 4) = r;
        } else {
            *(float4*)(out + (size_t)m * HSZ + o0 + tx * 4) = r;
        }
    }
}

// ---------------------------------------------------------------------------
// Flash attention, fp32. One block per (q-tile of 64 rows, b*h).
// Q staged once (scaled by 1/sqrt(64)=0.125), K/V tiles of 64 per iter.
// P reuses K's LDS buffer (S-phase done with K before P is written).
// LDS: 3 x 64x68 floats = 52 KB.
// ---------------------------------------------------------------------------
__global__ __launch_bounds__(256)
void attn_k(const float* __restrict__ Q, const float* __restrict__ K,
            const float* __restrict__ V, float* __restrict__ ctx) {
    __shared__ float Qs[64][68];    // [d][r]  (transposed)
    __shared__ float KPs[64][68];   // K: [d][c] (transposed), then P: [c][r]
    __shared__ float Vs[64][68];    // [c][d]  (natural)

    const int t  = threadIdx.x;
    const int tx = t & 15;          // col-direction
    const int ty = t >> 4;          // row-direction
    const int qt = blockIdx.x;      // 0..31
    const int bh = blockIdx.y;      // 0..31
    const int b_ = bh >> 4, h_ = bh & 15;

    const float* Qp = Q + ((size_t)bh * NN + qt * 64) * HD;
    const float* Kp = K + (size_t)bh * NN * HD;
    const float* Vp = V + (size_t)bh * NN * HD;

    // stage Q transposed & pre-scaled
#pragma unroll
    for (int rep = 0; rep < 4; ++rep) {
        int idx = rep * 256 + t;
        int row = idx >> 4, cc = (idx & 15) * 4;
        float4 q4 = *(const float4*)(Qp + row * HD + cc);
        Qs[cc + 0][row] = q4.x * 0.125f;
        Qs[cc + 1][row] = q4.y * 0.125f;
        Qs[cc + 2][row] = q4.z * 0.125f;
        Qs[cc + 3][row] = q4.w * 0.125f;
    }

    float m_i[4] = {-INFINITY, -INFINITY, -INFINITY, -INFINITY};
    float l_i[4] = {};
    float acc[4][4] = {};

    for (int kt = 0; kt < NN / 64; ++kt) {
        __syncthreads();            // prev PV reads done; Q staged (first iter)
        // stage K (transposed) and V (natural)
#pragma unroll
        for (int rep = 0; rep < 4; ++rep) {
            int idx = rep * 256 + t;
            int row = idx >> 4, cc = (idx & 15) * 4;
            float4 k4 = *(const float4*)(Kp + (size_t)(kt * 64 + row) * HD + cc);
            KPs[cc + 0][row] = k4.x;
            KPs[cc + 1][row] = k4.y;
            KPs[cc + 2][row] = k4.z;
            KPs[cc + 3][row] = k4.w;
            float4 v4 = *(const float4*)(Vp + (size_t)(kt * 64 + row) * HD + cc);
            *(float4*)&Vs[row][cc] = v4;
        }
        __syncthreads();

        // S = Q_tile @ K_tile^T (scale already folded into Q)
        float s[4][4] = {};
#pragma unroll 16
        for (int kk = 0; kk < 64; ++kk) {
            float4 av = *(const float4*)&Qs[kk][ty * 4];
            float4 bv = *(const float4*)&KPs[kk][tx * 4];
            float a_[4] = {av.x, av.y, av.z, av.w};
            float b_[4] = {bv.x, bv.y, bv.z, bv.w};
#pragma unroll
            for (int i = 0; i < 4; ++i)
#pragma unroll
                for (int j = 0; j < 4; ++j)
                    s[i][j] = fmaf(a_[i], b_[j], s[i][j]);
        }

        // online softmax (per-row stats; reduce over the 16-lane tx group)
#pragma unroll
        for (int i = 0; i < 4; ++i) {
            float pm = fmaxf(fmaxf(s[i][0], s[i][1]), fmaxf(s[i][2], s[i][3]));
            pm = fmaxf(pm, __shfl_xor(pm, 1));
            pm = fmaxf(pm, __shfl_xor(pm, 2));
            pm = fmaxf(pm, __shfl_xor(pm, 4));
            pm = fmaxf(pm, __shfl_xor(pm, 8));
            float mnew = fmaxf(m_i[i], pm);
            float a_   = expf(m_i[i] - mnew);   // first iter: exp(-inf)=0
            float ps = 0.f;
#pragma unroll
            for (int j = 0; j < 4; ++j) {
                s[i][j] = expf(s[i][j] - mnew);
                ps += s[i][j];
            }
            ps += __shfl_xor(ps, 1);
            ps += __shfl_xor(ps, 2);
            ps += __shfl_xor(ps, 4);
            ps += __shfl_xor(ps, 8);
            l_i[i] = l_i[i] * a_ + ps;
            m_i[i] = mnew;
#pragma unroll
            for (int j = 0; j < 4; ++j) acc[i][j] *= a_;
        }

        __syncthreads();            // everyone done reading K from KPs
        // write P transposed into KPs: Ps[c][r]
#pragma unroll
        for (int j = 0; j < 4; ++j)
#pragma unroll
            for (int i = 0; i < 4; ++i)
                KPs[tx * 4 + j][ty * 4 + i] = s[i][j];
        __syncthreads();

        // O += P @ V
#pragma unroll 16
        for (int kk = 0; kk < 64; ++kk) {
            float4 pv = *(const float4*)&KPs[kk][ty * 4];
            float4 vv = *(const float4*)&Vs[kk][tx * 4];
            float p_[4] = {pv.x, pv.y, pv.z, pv.w};
            float v_[4] = {vv.x, vv.y, vv.z, vv.w};
#pragma unroll
            for (int i = 0; i < 4; ++i)
#pragma unroll
                for (int j = 0; j < 4; ++j)
                    acc[i][j] = fmaf(p_[i], v_[j], acc[i][j]);
        }
    }

    // normalize and write ctx in [b][n][h*64+d] layout (ready for final proj)
#pragma unroll
    for (int i = 0; i < 4; ++i) {
        float inv = 1.f / l_i[i];
        int nn = qt * 64 + ty * 4 + i;
        float4 r = {acc[i][0] * inv, acc[i][1] * inv, acc[i][2] * inv, acc[i][3] * inv};
        *(float4*)(ctx + ((size_t)b_ * NN + nn) * HSZ + h_ * HD + tx * 4) = r;
    }
}

// ---------------------------------------------------------------------------
extern "C" void kernel_launch(void* const* d_in, const int* in_sizes, int n_in,
                              void* d_out, int out_size, void* d_ws, size_t ws_size,
                              hipStream_t stream) {
    (void)in_sizes; (void)n_in; (void)out_size; (void)ws_size;
    const float* hs = (const float*)d_in[0];
    const float* Wq = (const float*)d_in[1];
    const float* bq = (const float*)d_in[2];
    const float* Wk = (const float*)d_in[3];
    const float* bk = (const float*)d_in[4];
    const float* Wv = (const float*)d_in[5];
    const float* bv = (const float*)d_in[6];
    const float* Wp = (const float*)d_in[7];
    const float* bp = (const float*)d_in[8];

    float* ws = (float*)d_ws;
    const size_t QKV = (size_t)BB * NH * NN * HD;   // 4,194,304 floats
    float* q   = ws;
    float* k   = ws + QKV;
    float* v   = ws + 2 * QKV;
    float* ctx = ws + 3 * QKV;                      // [4096][1024]
    float* tab = ws + 4 * QKV;                      // [2048][64][2]
    // total ws use: (4*4194304 + 262144) * 4 B = 68.2 MB

    rope_table_k<<<dim3(NN), dim3(64), 0, stream>>>(tab);

    dim3 blk(256);
    dim3 gproj(HSZ / 64, (BB * NN) / 64);           // (16, 64)
    proj_k<<<gproj, blk, 0, stream>>>(hs, Wq, bq, q, tab, 0);
    proj_k<<<gproj, blk, 0, stream>>>(hs, Wk, bk, k, tab, 1);
    proj_k<<<gproj, blk, 0, stream>>>(hs, Wv, bv, v, tab, 2);

    dim3 gattn(NN / 64, BB * NH);                   // (32, 32)
    attn_k<<<gattn, blk, 0, stream>>>(q, k, v, ctx);

    proj_k<<<gproj, blk, 0, stream>>>(ctx, Wp, bp, (float*)d_out, tab, 3);
}

// Round 2
// 213.263 us; speedup vs baseline: 5.7022x; 5.7022x over previous
//
#include <hip/hip_runtime.h>
#include <math.h>

#define BB    2
#define NN    2048
#define HSZ   1024
#define NH    16
#define HD    64
#define SEGW  20

typedef unsigned short u16;
typedef unsigned int   u32;
using bf16x8 = __attribute__((ext_vector_type(8))) short;   // 8 bf16 in 4 VGPRs
using f32x4  = __attribute__((ext_vector_type(4))) float;

// float -> bf16 (RNE)
__device__ __forceinline__ u16 f2b(float f) {
    union { float f; u32 u; } x; x.f = f;
    u32 r = x.u + 0x7FFF + ((x.u >> 16) & 1);
    return (u16)(r >> 16);
}

// async global->LDS, 16B per lane; lds base must be wave-uniform
__device__ __forceinline__ void gload16(void* lds, const void* g) {
    __builtin_amdgcn_global_load_lds(
        (const __attribute__((address_space(1))) void*)g,
        (__attribute__((address_space(3))) void*)lds, 16, 0, 0);
}

// ---------------------------------------------------------------------------
// cast fp32 -> bf16: hs (4M) + 4 weights (1M each). 4 elems/thread.
// ---------------------------------------------------------------------------
__global__ __launch_bounds__(256)
void cast_k(const float* __restrict__ hs, const float* __restrict__ Wq,
            const float* __restrict__ Wk, const float* __restrict__ Wv,
            const float* __restrict__ Wp, u16* __restrict__ hsb,
            u16* __restrict__ wqb, u16* __restrict__ wkb,
            u16* __restrict__ wvb, u16* __restrict__ wpb) {
    size_t idx = ((size_t)blockIdx.x * 256 + threadIdx.x) * 4;
    const float* s; u16* d; size_t o;
    const size_t HSN = 4194304, WN = 1048576;
    if      (idx < HSN)          { s = hs; d = hsb; o = idx; }
    else if (idx < HSN + WN)     { s = Wq; d = wqb; o = idx - HSN; }
    else if (idx < HSN + 2*WN)   { s = Wk; d = wkb; o = idx - HSN - WN; }
    else if (idx < HSN + 3*WN)   { s = Wv; d = wvb; o = idx - HSN - 2*WN; }
    else                         { s = Wp; d = wpb; o = idx - HSN - 3*WN; }
    float4 v = *(const float4*)(s + o);
    u32 lo = f2b(v.x) | ((u32)f2b(v.y) << 16);
    u32 hi = f2b(v.z) | ((u32)f2b(v.w) << 16);
    *(uint2*)(d + o) = uint2{lo, hi};
}

// ---------------------------------------------------------------------------
// RoPE cos/sin table: tab[n][d] = {cos,sin}; dims 60..63 -> (1,0) identity.
// ---------------------------------------------------------------------------
__global__ void rope_table_k(float* __restrict__ tab) {
    int n = blockIdx.x, d = threadIdx.x;
    float c = 1.f, s = 0.f;
    if (d < 3 * SEGW) {
        int seg = d / SEGW;
        int jj  = (d % SEGW) % (SEGW / 2);
        int rem = n & 255;
        int pos = (seg == 0) ? (n >> 8) : ((seg == 1) ? (rem >> 4) : (rem & 15));
        float omega = powf(10000.f, -(float)jj / 10.f);
        float fr = (float)pos * omega;
        s = sinf(fr); c = cosf(fr);
    }
    tab[(n * 64 + d) * 2 + 0] = c;
    tab[(n * 64 + d) * 2 + 1] = s;
}

// ---------------------------------------------------------------------------
// bf16 MFMA GEMM: C[m,o] = sum_k X[m,k]*W[o,k] + bias[o]
// BM=128, BN=64, BK=32; 4 waves, each 64x32 (4x2 frags of 16x16).
// mode 0: +rope, write bf16 natural [bh][n][d]   (q / k)
// mode 2: write bf16 TRANSPOSED [bh][d][n]       (v)
// mode 3: write fp32 row-major [m][o]            (final out)
// ---------------------------------------------------------------------------
__global__ __launch_bounds__(256)
void proj_mfma_k(const u16* __restrict__ X, const u16* __restrict__ Wb,
                 const float* __restrict__ bias, void* __restrict__ out,
                 const float* __restrict__ tab, int mode) {
    __shared__ u16 As[128 * 32];   // [row m][k] 64B rows, linear (m97 layout)
    __shared__ u16 Bs[64 * 32];

    const int t  = threadIdx.x;
    const int w  = t >> 6;
    const int l  = t & 63;
    const int o0 = blockIdx.x * 64;
    const int m0 = blockIdx.y * 128;
    const int wr = (w >> 1) * 64;      // wave row offset in tile
    const int wc = (w & 1) * 32;       // wave col offset

    f32x4 acc[4][2] = {};

    for (int k0 = 0; k0 < HSZ; k0 += 32) {
        // stage A (8KB: 2 issues) + B (4KB: 1 issue)
#pragma unroll
        for (int s = 0; s < 2; ++s) {
            int chunk = s * 256 + (w << 6) + l;
            int row = chunk >> 2, c8 = (chunk & 3) * 8;
            gload16(As + (s * 256 + (w << 6)) * 8,
                    X + (size_t)(m0 + row) * HSZ + k0 + c8);
        }
        {
            int chunk = (w << 6) + l;
            int row = chunk >> 2, c8 = (chunk & 3) * 8;
            gload16(Bs + (w << 6) * 8,
                    Wb + (size_t)(o0 + row) * HSZ + k0 + c8);
        }
        __syncthreads();               // vmcnt drain + staging visible

        bf16x8 af[4], bfr[2];
#pragma unroll
        for (int i = 0; i < 4; ++i)
            af[i] = *(const bf16x8*)(As + (wr + i * 16 + (l & 15)) * 32 + (l >> 4) * 8);
#pragma unroll
        for (int j = 0; j < 2; ++j)
            bfr[j] = *(const bf16x8*)(Bs + (wc + j * 16 + (l & 15)) * 32 + (l >> 4) * 8);
#pragma unroll
        for (int i = 0; i < 4; ++i)
#pragma unroll
            for (int j = 0; j < 2; ++j)
                acc[i][j] = __builtin_amdgcn_mfma_f32_16x16x32_bf16(af[i], bfr[j], acc[i][j], 0, 0, 0);
        __syncthreads();               // reads done before next staging
    }

    // ---- epilogue ----
    const int h = o0 >> 6;             // one head per 64-wide col block
#pragma unroll
    for (int ct = 0; ct < 2; ++ct) {
        int oc = o0 + wc + ct * 16 + (l & 15);   // global out col
        int d  = oc & 63;
        float bv = bias[oc];
        if (mode == 2) {
            // V: transposed write [bh][d][n], 4 consecutive n packed (8B)
#pragma unroll
            for (int rt = 0; rt < 4; ++rt) {
                int base = m0 + wr + rt * 16 + (l >> 4) * 4;
                int b_ = base >> 11, n0 = base & (NN - 1);
                u16 e[4];
#pragma unroll
                for (int r = 0; r < 4; ++r) e[r] = f2b(acc[rt][ct][r] + bv);
                u32 lo = e[0] | ((u32)e[1] << 16);
                u32 hi = e[2] | ((u32)e[3] << 16);
                u16* vp = (u16*)out + (((size_t)b_ * NH + h) * HD + d) * NN + n0;
                *(uint2*)vp = uint2{lo, hi};
            }
        } else if (mode == 3) {
#pragma unroll
            for (int rt = 0; rt < 4; ++rt)
#pragma unroll
                for (int r = 0; r < 4; ++r) {
                    int m = m0 + wr + rt * 16 + (l >> 4) * 4 + r;
                    ((float*)out)[(size_t)m * HSZ + oc] = acc[rt][ct][r] + bv;
                }
        } else {
            // q/k: bias -> rope(fp32) -> bf16 natural [bh][n][d]
#pragma unroll
            for (int rt = 0; rt < 4; ++rt)
#pragma unroll
                for (int r = 0; r < 4; ++r) {
                    int m = m0 + wr + rt * 16 + (l >> 4) * 4 + r;
                    int n = m & (NN - 1), b_ = m >> 11;
                    float v = acc[rt][ct][r] + bv;
                    float2 cs = ((const float2*)tab)[n * 64 + d];
                    float part = __shfl_xor(v, 1);
                    float vr = (l & 1) ? fmaf(part, cs.y, v * cs.x)
                                       : fmaf(-part, cs.y, v * cs.x);
                    u16* qp = (u16*)out + (((size_t)b_ * NH + h) * NN + n) * HD + d;
                    *qp = f2b(vr);
                }
        }
    }
}

// ---------------------------------------------------------------------------
// MFMA flash attention. Grid (32 qtiles, 32 bh), 256 thr / 4 waves.
// QBLK=KVBLK=64. Tiles [64][64] bf16, 128B rows, XOR-swizzled c16^=(row&7)
// via pre-swizzled gload source + swizzled reads. Ps is per-wave private.
// ---------------------------------------------------------------------------
__global__ __launch_bounds__(256)
void attn_mfma_k(const u16* __restrict__ Qb, const u16* __restrict__ Kb,
                 const u16* __restrict__ Vtb, u16* __restrict__ ctxb) {
    __shared__ u16 Qs[64 * 64], Ks[64 * 64], Vs[64 * 64], Ps[64 * 64];

    const int t = threadIdx.x, w = t >> 6, l = t & 63;
    const int qt = blockIdx.x, bh = blockIdx.y;
    const int b_ = bh >> 4, h = bh & 15;

    const u16* Qg = Qb + ((size_t)bh * NN + qt * 64) * HD;
    const u16* Kg0 = Kb + (size_t)bh * NN * HD;
    const u16* Vg0 = Vtb + (size_t)bh * HD * NN;

    // stage Q (swizzled source, linear LDS dest)
#pragma unroll
    for (int s = 0; s < 2; ++s) {
        int chunk = s * 256 + (w << 6) + l;
        int row = chunk >> 3, c16 = chunk & 7;
        int sc = c16 ^ (row & 7);
        gload16(Qs + (s * 256 + (w << 6)) * 8, Qg + row * HD + sc * 8);
    }

    float m_i[4] = {-INFINITY, -INFINITY, -INFINITY, -INFINITY};
    float l_i[4] = {};
    f32x4 o_acc[4] = {};

    for (int kt = 0; kt < NN / 64; ++kt) {
        const u16* Kg = Kg0 + (size_t)(kt * 64) * HD;
        const u16* Vg = Vg0 + kt * 64;
#pragma unroll
        for (int s = 0; s < 2; ++s) {
            int chunk = s * 256 + (w << 6) + l;
            int row = chunk >> 3, c16 = chunk & 7;
            int sc = c16 ^ (row & 7);
            gload16(Ks + (s * 256 + (w << 6)) * 8, Kg + row * HD + sc * 8);
            gload16(Vs + (s * 256 + (w << 6)) * 8, Vg + (size_t)row * NN + sc * 8);
        }
        __syncthreads();               // staging done (prev PV done via tail barrier)

        // ---- S = Q K^T ----
        bf16x8 qf[2];
#pragma unroll
        for (int kk = 0; kk < 2; ++kk) {
            int row = w * 16 + (l & 15);
            int cb = (kk * 64 + (l >> 4) * 16) ^ ((row & 7) << 4);
            qf[kk] = *(const bf16x8*)((const char*)Qs + row * 128 + cb);
        }
        f32x4 sacc[4] = {};
#pragma unroll
        for (int ct = 0; ct < 4; ++ct)
#pragma unroll
            for (int kk = 0; kk < 2; ++kk) {
                int row = ct * 16 + (l & 15);
                int cb = (kk * 64 + (l >> 4) * 16) ^ ((row & 7) << 4);
                bf16x8 kf = *(const bf16x8*)((const char*)Ks + row * 128 + cb);
                sacc[ct] = __builtin_amdgcn_mfma_f32_16x16x32_bf16(qf[kk], kf, sacc[ct], 0, 0, 0);
            }

        // ---- online softmax (rows grouped in 16-lane sets) ----
#pragma unroll
        for (int r = 0; r < 4; ++r) {
            float mx = -INFINITY;
#pragma unroll
            for (int ct = 0; ct < 4; ++ct) {
                float sv = sacc[ct][r] * 0.125f;
                sacc[ct][r] = sv;
                mx = fmaxf(mx, sv);
            }
            mx = fmaxf(mx, __shfl_xor(mx, 1));
            mx = fmaxf(mx, __shfl_xor(mx, 2));
            mx = fmaxf(mx, __shfl_xor(mx, 4));
            mx = fmaxf(mx, __shfl_xor(mx, 8));
            float mn = fmaxf(m_i[r], mx);
            float alpha = __expf(m_i[r] - mn);
            float ps = 0.f;
#pragma unroll
            for (int ct = 0; ct < 4; ++ct) {
                float p = __expf(sacc[ct][r] - mn);
                sacc[ct][r] = p;
                ps += p;
            }
            ps += __shfl_xor(ps, 1);
            ps += __shfl_xor(ps, 2);
            ps += __shfl_xor(ps, 4);
            ps += __shfl_xor(ps, 8);
            l_i[r] = l_i[r] * alpha + ps;
            m_i[r] = mn;
#pragma unroll
            for (int dt = 0; dt < 4; ++dt) o_acc[dt][r] *= alpha;
        }

        // ---- P -> LDS (bf16, swizzled; wave-private rows) ----
#pragma unroll
        for (int ct = 0; ct < 4; ++ct)
#pragma unroll
            for (int r = 0; r < 4; ++r) {
                int row = w * 16 + (l >> 4) * 4 + r;
                int cb = ((ct * 16 + (l & 15)) * 2) ^ ((row & 7) << 4);
                *(u16*)((char*)Ps + row * 128 + cb) = f2b(sacc[ct][r]);
            }

        // ---- O += P V ----
#pragma unroll
        for (int kk = 0; kk < 2; ++kk) {
            int prow = w * 16 + (l & 15);
            int pcb = (kk * 64 + (l >> 4) * 16) ^ ((prow & 7) << 4);
            bf16x8 pf = *(const bf16x8*)((const char*)Ps + prow * 128 + pcb);
#pragma unroll
            for (int dt = 0; dt < 4; ++dt) {
                int vrow = dt * 16 + (l & 15);
                int vcb = (kk * 64 + (l >> 4) * 16) ^ ((vrow & 7) << 4);
                bf16x8 vf = *(const bf16x8*)((const char*)Vs + vrow * 128 + vcb);
                o_acc[dt] = __builtin_amdgcn_mfma_f32_16x16x32_bf16(pf, vf, o_acc[dt], 0, 0, 0);
            }
        }
        __syncthreads();               // all waves done reading Ks/Vs before restage
    }

    // ---- normalize + write ctx bf16 [b][n][h*64+d] ----
#pragma unroll
    for (int r = 0; r < 4; ++r) {
        float inv = 1.f / l_i[r];
        int n = qt * 64 + w * 16 + (l >> 4) * 4 + r;
#pragma unroll
        for (int dt = 0; dt < 4; ++dt) {
            int d = dt * 16 + (l & 15);
            ctxb[((size_t)b_ * NN + n) * HSZ + h * HD + d] = f2b(o_acc[dt][r] * inv);
        }
    }
}

// ---------------------------------------------------------------------------
extern "C" void kernel_launch(void* const* d_in, const int* in_sizes, int n_in,
                              void* d_out, int out_size, void* d_ws, size_t ws_size,
                              hipStream_t stream) {
    (void)in_sizes; (void)n_in; (void)out_size; (void)ws_size;
    const float* hs = (const float*)d_in[0];
    const float* Wq = (const float*)d_in[1];
    const float* bq = (const float*)d_in[2];
    const float* Wk = (const float*)d_in[3];
    const float* bk = (const float*)d_in[4];
    const float* Wv = (const float*)d_in[5];
    const float* bv = (const float*)d_in[6];
    const float* Wp = (const float*)d_in[7];
    const float* bp = (const float*)d_in[8];

    char* ws = (char*)d_ws;
    u16*   hsb  = (u16*)(ws);                      //  8 MB  [4096][1024] bf16
    u16*   Wqb  = (u16*)(ws + 8388608);            //  2 MB
    u16*   Wkb  = (u16*)(ws + 10485760);
    u16*   Wvb  = (u16*)(ws + 12582912);
    u16*   Wpb  = (u16*)(ws + 14680064);
    u16*   qb   = (u16*)(ws + 16777216);           //  8 MB  [32][2048][64]
    u16*   kb   = (u16*)(ws + 25165824);
    u16*   vtb  = (u16*)(ws + 33554432);           //  8 MB  [32][64][2048]
    u16*   ctxb = (u16*)(ws + 41943040);           //  8 MB  [4096][1024]
    float* tab  = (float*)(ws + 50331648);         //  1 MB  [2048][64][2]

    cast_k<<<8192, 256, 0, stream>>>(hs, Wq, Wk, Wv, Wp, hsb, Wqb, Wkb, Wvb, Wpb);
    rope_table_k<<<NN, 64, 0, stream>>>(tab);

    dim3 gproj(HSZ / 64, (BB * NN) / 128);         // (16, 32)
    proj_mfma_k<<<gproj, 256, 0, stream>>>(hsb, Wqb, bq, qb, tab, 0);
    proj_mfma_k<<<gproj, 256, 0, stream>>>(hsb, Wkb, bk, kb, tab, 0);
    proj_mfma_k<<<gproj, 256, 0, stream>>>(hsb, Wvb, bv, vtb, tab, 2);

    attn_mfma_k<<<dim3(NN / 64, BB * NH), 256, 0, stream>>>(qb, kb, vtb, ctxb);

    proj_mfma_k<<<gproj, 256, 0, stream>>>(ctxb, Wpb, bp, d_out, tab, 3);
}

// Round 3
// 211.312 us; speedup vs baseline: 5.7548x; 1.0092x over previous
//
#include <hip/hip_runtime.h>
#include <math.h>

#define BB    2
#define NN    2048
#define HSZ   1024
#define NH    16
#define HD    64
#define SEGW  20

#define LOG2E  1.4426950408889634f
#define QSCALE (0.125f * LOG2E)     // folded into Q at projection time
#define DTHR   8.0f                 // defer-max threshold (log2 units)

typedef unsigned short u16;
typedef unsigned int   u32;
using bf16x8 = __attribute__((ext_vector_type(8))) short;
using f32x4  = __attribute__((ext_vector_type(4))) float;

// float -> bf16 (RNE)
__device__ __forceinline__ u16 f2b(float f) {
    union { float f; u32 u; } x; x.f = f;
    u32 r = x.u + 0x7FFF + ((x.u >> 16) & 1);
    return (u16)(r >> 16);
}

// async global->LDS, 16B/lane; lds base wave-uniform
__device__ __forceinline__ void gload16(void* lds, const void* g) {
    __builtin_amdgcn_global_load_lds(
        (const __attribute__((address_space(1))) void*)g,
        (__attribute__((address_space(3))) void*)lds, 16, 0, 0);
}

// ---------------------------------------------------------------------------
__global__ __launch_bounds__(256)
void cast_k(const float* __restrict__ hs, const float* __restrict__ Wq,
            const float* __restrict__ Wk, const float* __restrict__ Wv,
            const float* __restrict__ Wp, u16* __restrict__ hsb,
            u16* __restrict__ wqb, u16* __restrict__ wkb,
            u16* __restrict__ wvb, u16* __restrict__ wpb) {
    size_t idx = ((size_t)blockIdx.x * 256 + threadIdx.x) * 4;
    const float* s; u16* d; size_t o;
    const size_t HSN = 4194304, WN = 1048576;
    if      (idx < HSN)          { s = hs; d = hsb; o = idx; }
    else if (idx < HSN + WN)     { s = Wq; d = wqb; o = idx - HSN; }
    else if (idx < HSN + 2*WN)   { s = Wk; d = wkb; o = idx - HSN - WN; }
    else if (idx < HSN + 3*WN)   { s = Wv; d = wvb; o = idx - HSN - 2*WN; }
    else                         { s = Wp; d = wpb; o = idx - HSN - 3*WN; }
    float4 v = *(const float4*)(s + o);
    u32 lo = f2b(v.x) | ((u32)f2b(v.y) << 16);
    u32 hi = f2b(v.z) | ((u32)f2b(v.w) << 16);
    *(uint2*)(d + o) = uint2{lo, hi};
}

// ---------------------------------------------------------------------------
__global__ void rope_table_k(float* __restrict__ tab) {
    int n = blockIdx.x, d = threadIdx.x;
    float c = 1.f, s = 0.f;
    if (d < 3 * SEGW) {
        int seg = d / SEGW;
        int jj  = (d % SEGW) % (SEGW / 2);
        int rem = n & 255;
        int pos = (seg == 0) ? (n >> 8) : ((seg == 1) ? (rem >> 4) : (rem & 15));
        float omega = powf(10000.f, -(float)jj / 10.f);
        float fr = (float)pos * omega;
        s = sinf(fr); c = cosf(fr);
    }
    tab[(n * 64 + d) * 2 + 0] = c;
    tab[(n * 64 + d) * 2 + 1] = s;
}

// ---------------------------------------------------------------------------
// Shared GEMM body: C[m,o] = sum_k X[m,k]*W[o,k] + bias[o]
// BM=128, BN=64, BK=32, double-buffered staging, 1 barrier/iter.
// mode 0: rope + QSCALE, bf16 [bh][n][d]   (q)
// mode 1: rope,          bf16 [bh][n][d]   (k)
// mode 2: plain,         bf16 [bh][d][n]   (v, transposed)
// mode 3: plain,         fp32 [m][o]       (final out)
// ---------------------------------------------------------------------------
__device__ __forceinline__
void gemm_body(const u16* __restrict__ X, const u16* __restrict__ Wb,
               const float* __restrict__ bias, void* __restrict__ out,
               const float* __restrict__ tab, int mode) {
    __shared__ u16 As[2][128 * 32];
    __shared__ u16 Bs[2][64 * 32];

    const int t  = threadIdx.x;
    const int w  = t >> 6;
    const int l  = t & 63;
    const int o0 = blockIdx.x * 64;
    const int m0 = blockIdx.y * 128;
    const int wr = (w >> 1) * 64;
    const int wc = (w & 1) * 32;

    // staging addresses (fixed per lane)
    const int chA0 = (w << 6) + l;            // A chunk ids: chA0, chA0+256
    const int rA0 = chA0 >> 2,        cA0 = (chA0 & 3) * 8;
    const int rA1 = (chA0 + 256) >> 2, cA1 = (chA0 & 3) * 8;
    const int rB  = chA0 >> 2,        cB  = (chA0 & 3) * 8;

    f32x4 acc[4][2] = {};

    // prologue: stage k0=0 into buf 0
    gload16(As[0] + ((w << 6)) * 8,       X  + (size_t)(m0 + rA0) * HSZ + cA0);
    gload16(As[0] + (256 + (w << 6)) * 8, X  + (size_t)(m0 + rA1) * HSZ + cA1);
    gload16(Bs[0] + ((w << 6)) * 8,       Wb + (size_t)(o0 + rB) * HSZ + cB);
    __syncthreads();

    int cur = 0;
    for (int k0 = 0; k0 < HSZ; k0 += 32, cur ^= 1) {
        if (k0 + 32 < HSZ) {    // prefetch next tile into other buffer
            int kn = k0 + 32;
            gload16(As[cur ^ 1] + ((w << 6)) * 8,       X  + (size_t)(m0 + rA0) * HSZ + kn + cA0);
            gload16(As[cur ^ 1] + (256 + (w << 6)) * 8, X  + (size_t)(m0 + rA1) * HSZ + kn + cA1);
            gload16(Bs[cur ^ 1] + ((w << 6)) * 8,       Wb + (size_t)(o0 + rB) * HSZ + kn + cB);
        }
        bf16x8 af[4], bfr[2];
#pragma unroll
        for (int i = 0; i < 4; ++i)
            af[i] = *(const bf16x8*)(As[cur] + (wr + i * 16 + (l & 15)) * 32 + (l >> 4) * 8);
#pragma unroll
        for (int j = 0; j < 2; ++j)
            bfr[j] = *(const bf16x8*)(Bs[cur] + (wc + j * 16 + (l & 15)) * 32 + (l >> 4) * 8);
#pragma unroll
        for (int i = 0; i < 4; ++i)
#pragma unroll
            for (int j = 0; j < 2; ++j)
                acc[i][j] = __builtin_amdgcn_mfma_f32_16x16x32_bf16(af[i], bfr[j], acc[i][j], 0, 0, 0);
        __syncthreads();        // drains prefetch (in flight during compute) + joins waves
    }

    // ---- epilogue ----
    const int h = o0 >> 6;
#pragma unroll
    for (int ct = 0; ct < 2; ++ct) {
        int oc = o0 + wc + ct * 16 + (l & 15);
        int d  = oc & 63;
        float bv = bias[oc];
        if (mode == 2) {
#pragma unroll
            for (int rt = 0; rt < 4; ++rt) {
                int base = m0 + wr + rt * 16 + (l >> 4) * 4;
                int b_ = base >> 11, n0 = base & (NN - 1);
                u16 e[4];
#pragma unroll
                for (int r = 0; r < 4; ++r) e[r] = f2b(acc[rt][ct][r] + bv);
                u32 lo = e[0] | ((u32)e[1] << 16);
                u32 hi = e[2] | ((u32)e[3] << 16);
                u16* vp = (u16*)out + (((size_t)b_ * NH + h) * HD + d) * NN + n0;
                *(uint2*)vp = uint2{lo, hi};
            }
        } else if (mode == 3) {
#pragma unroll
            for (int rt = 0; rt < 4; ++rt)
#pragma unroll
                for (int r = 0; r < 4; ++r) {
                    int m = m0 + wr + rt * 16 + (l >> 4) * 4 + r;
                    ((float*)out)[(size_t)m * HSZ + oc] = acc[rt][ct][r] + bv;
                }
        } else {
            float scl = (mode == 0) ? QSCALE : 1.f;
#pragma unroll
            for (int rt = 0; rt < 4; ++rt)
#pragma unroll
                for (int r = 0; r < 4; ++r) {
                    int m = m0 + wr + rt * 16 + (l >> 4) * 4 + r;
                    int n = m & (NN - 1), b_ = m >> 11;
                    float v = acc[rt][ct][r] + bv;
                    float2 cs = ((const float2*)tab)[n * 64 + d];
                    float part = __shfl_xor(v, 1);
                    float vr = (l & 1) ? fmaf(part, cs.y, v * cs.x)
                                       : fmaf(-part, cs.y, v * cs.x);
                    u16* qp = (u16*)out + (((size_t)b_ * NH + h) * NN + n) * HD + d;
                    *qp = f2b(vr * scl);
                }
        }
    }
}

__global__ __launch_bounds__(256)
void qkv_k(const u16* __restrict__ X,
           const u16* __restrict__ Wq, const u16* __restrict__ Wk, const u16* __restrict__ Wv,
           const float* __restrict__ bq, const float* __restrict__ bk, const float* __restrict__ bv,
           u16* __restrict__ qo, u16* __restrict__ ko, u16* __restrict__ vo,
           const float* __restrict__ tab) {
    int z = blockIdx.z;
    const u16* W   = (z == 0) ? Wq : (z == 1) ? Wk : Wv;
    const float* b = (z == 0) ? bq : (z == 1) ? bk : bv;
    u16* o         = (z == 0) ? qo : (z == 1) ? ko : vo;
    gemm_body(X, W, b, o, tab, z);
}

__global__ __launch_bounds__(256)
void projo_k(const u16* __restrict__ X, const u16* __restrict__ W,
             const float* __restrict__ b, float* __restrict__ out) {
    gemm_body(X, W, b, out, nullptr, 3);
}

// ---------------------------------------------------------------------------
// MFMA flash attention, double-buffered K/V, 1 barrier/iter, exp2-domain
// softmax with defer-max, setprio around MFMA, XCD-aware block swizzle.
// Q pre-scaled by 0.125*log2e at projection time.
// ---------------------------------------------------------------------------
__global__ __launch_bounds__(256)
void attn_mfma_k(const u16* __restrict__ Qb, const u16* __restrict__ Kb,
                 const u16* __restrict__ Vtb, u16* __restrict__ ctxb) {
    __shared__ u16 Qs[64 * 64];
    __shared__ u16 Ks[2][64 * 64];
    __shared__ u16 Vs[2][64 * 64];
    __shared__ u16 Ps[64 * 64];

    const int t = threadIdx.x, w = t >> 6, l = t & 63;
    // XCD swizzle: all 32 q-tiles of one bh land on one XCD -> K/V L2-resident
    int f   = blockIdx.y * 32 + blockIdx.x;
    int bh  = (f & 7) * 4 + ((f >> 3) & 3);
    int qt  = f >> 5;
    const int b_ = bh >> 4, h = bh & 15;

    const u16* Qg  = Qb + ((size_t)bh * NN + qt * 64) * HD;
    const u16* Kg0 = Kb + (size_t)bh * NN * HD;
    const u16* Vg0 = Vtb + (size_t)bh * HD * NN;

    // fixed per-lane staging coords (swizzled source, linear LDS dest)
    const int ch0 = (w << 6) + l;
    const int r0 = ch0 >> 3,         s0 = (ch0 & 7) ^ (r0 & 7);
    const int r1 = (ch0 + 256) >> 3, s1 = (ch0 & 7) ^ (r1 & 7);

    // stage Q + K/V tile 0
    gload16(Qs + ((w << 6)) * 8,       Qg + r0 * HD + s0 * 8);
    gload16(Qs + (256 + (w << 6)) * 8, Qg + r1 * HD + s1 * 8);
    gload16(Ks[0] + ((w << 6)) * 8,       Kg0 + (size_t)r0 * HD + s0 * 8);
    gload16(Ks[0] + (256 + (w << 6)) * 8, Kg0 + (size_t)r1 * HD + s1 * 8);
    gload16(Vs[0] + ((w << 6)) * 8,       Vg0 + (size_t)r0 * NN + s0 * 8);
    gload16(Vs[0] + (256 + (w << 6)) * 8, Vg0 + (size_t)r1 * NN + s1 * 8);
    __syncthreads();

    float m_i[4] = {-INFINITY, -INFINITY, -INFINITY, -INFINITY};
    float l_i[4] = {};
    f32x4 o_acc[4] = {};

    int cur = 0;
    for (int kt = 0; kt < NN / 64; ++kt, cur ^= 1) {
        if (kt + 1 < NN / 64) {    // prefetch next K/V tile into other buffer
            const u16* Kg = Kg0 + (size_t)((kt + 1) * 64) * HD;
            const u16* Vg = Vg0 + (kt + 1) * 64;
            gload16(Ks[cur ^ 1] + ((w << 6)) * 8,       Kg + (size_t)r0 * HD + s0 * 8);
            gload16(Ks[cur ^ 1] + (256 + (w << 6)) * 8, Kg + (size_t)r1 * HD + s1 * 8);
            gload16(Vs[cur ^ 1] + ((w << 6)) * 8,       Vg + (size_t)r0 * NN + s0 * 8);
            gload16(Vs[cur ^ 1] + (256 + (w << 6)) * 8, Vg + (size_t)r1 * NN + s1 * 8);
        }

        // ---- S = Q K^T (log2-domain: Q pre-scaled) ----
        bf16x8 qf[2];
#pragma unroll
        for (int kk = 0; kk < 2; ++kk) {
            int row = w * 16 + (l & 15);
            int cb = (kk * 64 + (l >> 4) * 16) ^ ((row & 7) << 4);
            qf[kk] = *(const bf16x8*)((const char*)Qs + row * 128 + cb);
        }
        f32x4 sacc[4] = {};
        __builtin_amdgcn_s_setprio(1);
#pragma unroll
        for (int ct = 0; ct < 4; ++ct)
#pragma unroll
            for (int kk = 0; kk < 2; ++kk) {
                int row = ct * 16 + (l & 15);
                int cb = (kk * 64 + (l >> 4) * 16) ^ ((row & 7) << 4);
                bf16x8 kf = *(const bf16x8*)((const char*)Ks[cur] + row * 128 + cb);
                sacc[ct] = __builtin_amdgcn_mfma_f32_16x16x32_bf16(qf[kk], kf, sacc[ct], 0, 0, 0);
            }
        __builtin_amdgcn_s_setprio(0);

        // ---- online softmax (exp2 domain) ----
        float mx[4];
#pragma unroll
        for (int r = 0; r < 4; ++r) {
            float m0_ = fmaxf(fmaxf(sacc[0][r], sacc[1][r]), fmaxf(sacc[2][r], sacc[3][r]));
            m0_ = fmaxf(m0_, __shfl_xor(m0_, 1));
            m0_ = fmaxf(m0_, __shfl_xor(m0_, 2));
            m0_ = fmaxf(m0_, __shfl_xor(m0_, 4));
            m0_ = fmaxf(m0_, __shfl_xor(m0_, 8));
            mx[r] = m0_;
        }
        bool grow = (mx[0] > m_i[0] + DTHR) | (mx[1] > m_i[1] + DTHR) |
                    (mx[2] > m_i[2] + DTHR) | (mx[3] > m_i[3] + DTHR);
        if (__any(grow)) {       // rescale path (rare after tile 0)
#pragma unroll
            for (int r = 0; r < 4; ++r) {
                float mn = fmaxf(m_i[r], mx[r]);
                float alpha = __builtin_amdgcn_exp2f(m_i[r] - mn);
                m_i[r] = mn;
                l_i[r] *= alpha;
#pragma unroll
                for (int dt = 0; dt < 4; ++dt) o_acc[dt][r] *= alpha;
            }
        }
#pragma unroll
        for (int r = 0; r < 4; ++r) {
            float ps = 0.f;
#pragma unroll
            for (int ct = 0; ct < 4; ++ct) {
                float p = __builtin_amdgcn_exp2f(sacc[ct][r] - m_i[r]);
                sacc[ct][r] = p;
                ps += p;
            }
            ps += __shfl_xor(ps, 1);
            ps += __shfl_xor(ps, 2);
            ps += __shfl_xor(ps, 4);
            ps += __shfl_xor(ps, 8);
            l_i[r] += ps;
        }

        // ---- P -> LDS (bf16, swizzled, wave-private rows) ----
#pragma unroll
        for (int ct = 0; ct < 4; ++ct)
#pragma unroll
            for (int r = 0; r < 4; ++r) {
                int row = w * 16 + (l >> 4) * 4 + r;
                int cb = ((ct * 16 + (l & 15)) * 2) ^ ((row & 7) << 4);
                *(u16*)((char*)Ps + row * 128 + cb) = f2b(sacc[ct][r]);
            }

        // ---- O += P V ----
        __builtin_amdgcn_s_setprio(1);
#pragma unroll
        for (int kk = 0; kk < 2; ++kk) {
            int prow = w * 16 + (l & 15);
            int pcb = (kk * 64 + (l >> 4) * 16) ^ ((prow & 7) << 4);
            bf16x8 pf = *(const bf16x8*)((const char*)Ps + prow * 128 + pcb);
#pragma unroll
            for (int dt = 0; dt < 4; ++dt) {
                int vrow = dt * 16 + (l & 15);
                int vcb = (kk * 64 + (l >> 4) * 16) ^ ((vrow & 7) << 4);
                bf16x8 vf = *(const bf16x8*)((const char*)Vs[cur] + vrow * 128 + vcb);
                o_acc[dt] = __builtin_amdgcn_mfma_f32_16x16x32_bf16(pf, vf, o_acc[dt], 0, 0, 0);
            }
        }
        __builtin_amdgcn_s_setprio(0);
        __syncthreads();   // drains prefetch (hidden under compute) + joins waves
    }

    // ---- normalize + write ctx bf16 [b][n][h*64+d] ----
#pragma unroll
    for (int r = 0; r < 4; ++r) {
        float inv = 1.f / l_i[r];
        int n = qt * 64 + w * 16 + (l >> 4) * 4 + r;
#pragma unroll
        for (int dt = 0; dt < 4; ++dt) {
            int d = dt * 16 + (l & 15);
            ctxb[((size_t)b_ * NN + n) * HSZ + h * HD + d] = f2b(o_acc[dt][r] * inv);
        }
    }
}

// ---------------------------------------------------------------------------
extern "C" void kernel_launch(void* const* d_in, const int* in_sizes, int n_in,
                              void* d_out, int out_size, void* d_ws, size_t ws_size,
                              hipStream_t stream) {
    (void)in_sizes; (void)n_in; (void)out_size; (void)ws_size;
    const float* hs = (const float*)d_in[0];
    const float* Wq = (const float*)d_in[1];
    const float* bq = (const float*)d_in[2];
    const float* Wk = (const float*)d_in[3];
    const float* bk = (const float*)d_in[4];
    const float* Wv = (const float*)d_in[5];
    const float* bv = (const float*)d_in[6];
    const float* Wp = (const float*)d_in[7];
    const float* bp = (const float*)d_in[8];

    char* ws = (char*)d_ws;
    u16*   hsb  = (u16*)(ws);
    u16*   Wqb  = (u16*)(ws + 8388608);
    u16*   Wkb  = (u16*)(ws + 10485760);
    u16*   Wvb  = (u16*)(ws + 12582912);
    u16*   Wpb  = (u16*)(ws + 14680064);
    u16*   qb   = (u16*)(ws + 16777216);
    u16*   kb   = (u16*)(ws + 25165824);
    u16*   vtb  = (u16*)(ws + 33554432);
    u16*   ctxb = (u16*)(ws + 41943040);
    float* tab  = (float*)(ws + 50331648);

    cast_k<<<8192, 256, 0, stream>>>(hs, Wq, Wk, Wv, Wp, hsb, Wqb, Wkb, Wvb, Wpb);
    rope_table_k<<<NN, 64, 0, stream>>>(tab);

    qkv_k<<<dim3(HSZ / 64, (BB * NN) / 128, 3), 256, 0, stream>>>(
        hsb, Wqb, Wkb, Wvb, bq, bk, bv, qb, kb, vtb, tab);

    attn_mfma_k<<<dim3(NN / 64, BB * NH), 256, 0, stream>>>(qb, kb, vtb, ctxb);

    projo_k<<<dim3(HSZ / 64, (BB * NN) / 128), 256, 0, stream>>>(ctxb, Wpb, bp, (float*)d_out);
}

// Round 4
// 159.670 us; speedup vs baseline: 7.6161x; 1.3234x over previous
//
#include <hip/hip_runtime.h>
#include <hip/hip_bf16.h>
#include <math.h>

#define BB    2
#define NN    2048
#define HSZ   1024
#define NH    16
#define HD    64
#define SEGW  20

#define LOG2E  1.4426950408889634f
#define QSCALE (0.125f * LOG2E)     // folded into Q at projection time
#define DTHR   8.0f                 // defer-max threshold (log2 units)

typedef unsigned short u16;
typedef unsigned int   u32;
using bf16x8 = __attribute__((ext_vector_type(8))) short;
using f32x4  = __attribute__((ext_vector_type(4))) float;

// float -> bf16 (RNE), manual (used in non-hot epilogues)
__device__ __forceinline__ u16 f2b(float f) {
    union { float f; u32 u; } x; x.f = f;
    u32 r = x.u + 0x7FFF + ((x.u >> 16) & 1);
    return (u16)(r >> 16);
}
// float -> bf16 via compiler cvt (hot path)
__device__ __forceinline__ u16 f2bc(float f) {
    __hip_bfloat16 h = __float2bfloat16(f);
    return *reinterpret_cast<u16*>(&h);
}

// async global->LDS, 16B/lane; lds base wave-uniform
__device__ __forceinline__ void gload16(void* lds, const void* g) {
    __builtin_amdgcn_global_load_lds(
        (const __attribute__((address_space(1))) void*)g,
        (__attribute__((address_space(3))) void*)lds, 16, 0, 0);
}

// ---------------------------------------------------------------------------
__global__ __launch_bounds__(256)
void cast_k(const float* __restrict__ hs, const float* __restrict__ Wq,
            const float* __restrict__ Wk, const float* __restrict__ Wv,
            const float* __restrict__ Wp, u16* __restrict__ hsb,
            u16* __restrict__ wqb, u16* __restrict__ wkb,
            u16* __restrict__ wvb, u16* __restrict__ wpb) {
    size_t idx = ((size_t)blockIdx.x * 256 + threadIdx.x) * 4;
    const float* s; u16* d; size_t o;
    const size_t HSN = 4194304, WN = 1048576;
    if      (idx < HSN)          { s = hs; d = hsb; o = idx; }
    else if (idx < HSN + WN)     { s = Wq; d = wqb; o = idx - HSN; }
    else if (idx < HSN + 2*WN)   { s = Wk; d = wkb; o = idx - HSN - WN; }
    else if (idx < HSN + 3*WN)   { s = Wv; d = wvb; o = idx - HSN - 2*WN; }
    else                         { s = Wp; d = wpb; o = idx - HSN - 3*WN; }
    float4 v = *(const float4*)(s + o);
    u32 lo = f2b(v.x) | ((u32)f2b(v.y) << 16);
    u32 hi = f2b(v.z) | ((u32)f2b(v.w) << 16);
    *(uint2*)(d + o) = uint2{lo, hi};
}

// ---------------------------------------------------------------------------
__global__ void rope_table_k(float* __restrict__ tab) {
    int n = blockIdx.x, d = threadIdx.x;
    float c = 1.f, s = 0.f;
    if (d < 3 * SEGW) {
        int seg = d / SEGW;
        int jj  = (d % SEGW) % (SEGW / 2);
        int rem = n & 255;
        int pos = (seg == 0) ? (n >> 8) : ((seg == 1) ? (rem >> 4) : (rem & 15));
        float omega = powf(10000.f, -(float)jj / 10.f);
        float fr = (float)pos * omega;
        s = sinf(fr); c = cosf(fr);
    }
    tab[(n * 64 + d) * 2 + 0] = c;
    tab[(n * 64 + d) * 2 + 1] = s;
}

// ---------------------------------------------------------------------------
// Shared GEMM body: C[m,o] = sum_k X[m,k]*W[o,k] + bias[o]
// BM=128, BN=64, BK=32, double-buffered staging, 1 barrier/iter.
// mode 0: rope + QSCALE, bf16 [bh][n][d]   (q)
// mode 1: rope,          bf16 [bh][n][d]   (k)
// mode 2: plain,         bf16 [bh][d][n]   (v, transposed)
// mode 3: plain,         fp32 [m][o]       (final out)
// ---------------------------------------------------------------------------
__device__ __forceinline__
void gemm_body(const u16* __restrict__ X, const u16* __restrict__ Wb,
               const float* __restrict__ bias, void* __restrict__ out,
               const float* __restrict__ tab, int mode) {
    __shared__ u16 As[2][128 * 32];
    __shared__ u16 Bs[2][64 * 32];

    const int t  = threadIdx.x;
    const int w  = t >> 6;
    const int l  = t & 63;
    const int o0 = blockIdx.x * 64;
    const int m0 = blockIdx.y * 128;
    const int wr = (w >> 1) * 64;
    const int wc = (w & 1) * 32;

    const int chA0 = (w << 6) + l;
    const int rA0 = chA0 >> 2,         cA0 = (chA0 & 3) * 8;
    const int rA1 = (chA0 + 256) >> 2, cA1 = (chA0 & 3) * 8;
    const int rB  = chA0 >> 2,         cB  = (chA0 & 3) * 8;

    f32x4 acc[4][2] = {};

    gload16(As[0] + ((w << 6)) * 8,       X  + (size_t)(m0 + rA0) * HSZ + cA0);
    gload16(As[0] + (256 + (w << 6)) * 8, X  + (size_t)(m0 + rA1) * HSZ + cA1);
    gload16(Bs[0] + ((w << 6)) * 8,       Wb + (size_t)(o0 + rB) * HSZ + cB);
    __syncthreads();

    int cur = 0;
    for (int k0 = 0; k0 < HSZ; k0 += 32, cur ^= 1) {
        if (k0 + 32 < HSZ) {
            int kn = k0 + 32;
            gload16(As[cur ^ 1] + ((w << 6)) * 8,       X  + (size_t)(m0 + rA0) * HSZ + kn + cA0);
            gload16(As[cur ^ 1] + (256 + (w << 6)) * 8, X  + (size_t)(m0 + rA1) * HSZ + kn + cA1);
            gload16(Bs[cur ^ 1] + ((w << 6)) * 8,       Wb + (size_t)(o0 + rB) * HSZ + kn + cB);
        }
        bf16x8 af[4], bfr[2];
#pragma unroll
        for (int i = 0; i < 4; ++i)
            af[i] = *(const bf16x8*)(As[cur] + (wr + i * 16 + (l & 15)) * 32 + (l >> 4) * 8);
#pragma unroll
        for (int j = 0; j < 2; ++j)
            bfr[j] = *(const bf16x8*)(Bs[cur] + (wc + j * 16 + (l & 15)) * 32 + (l >> 4) * 8);
#pragma unroll
        for (int i = 0; i < 4; ++i)
#pragma unroll
            for (int j = 0; j < 2; ++j)
                acc[i][j] = __builtin_amdgcn_mfma_f32_16x16x32_bf16(af[i], bfr[j], acc[i][j], 0, 0, 0);
        __syncthreads();
    }

    // ---- epilogue ----
    const int h = o0 >> 6;
#pragma unroll
    for (int ct = 0; ct < 2; ++ct) {
        int oc = o0 + wc + ct * 16 + (l & 15);
        int d  = oc & 63;
        float bv = bias[oc];
        if (mode == 2) {
#pragma unroll
            for (int rt = 0; rt < 4; ++rt) {
                int base = m0 + wr + rt * 16 + (l >> 4) * 4;
                int b_ = base >> 11, n0 = base & (NN - 1);
                u16 e[4];
#pragma unroll
                for (int r = 0; r < 4; ++r) e[r] = f2b(acc[rt][ct][r] + bv);
                u32 lo = e[0] | ((u32)e[1] << 16);
                u32 hi = e[2] | ((u32)e[3] << 16);
                u16* vp = (u16*)out + (((size_t)b_ * NH + h) * HD + d) * NN + n0;
                *(uint2*)vp = uint2{lo, hi};
            }
        } else if (mode == 3) {
#pragma unroll
            for (int rt = 0; rt < 4; ++rt)
#pragma unroll
                for (int r = 0; r < 4; ++r) {
                    int m = m0 + wr + rt * 16 + (l >> 4) * 4 + r;
                    ((float*)out)[(size_t)m * HSZ + oc] = acc[rt][ct][r] + bv;
                }
        } else {
            float scl = (mode == 0) ? QSCALE : 1.f;
#pragma unroll
            for (int rt = 0; rt < 4; ++rt)
#pragma unroll
                for (int r = 0; r < 4; ++r) {
                    int m = m0 + wr + rt * 16 + (l >> 4) * 4 + r;
                    int n = m & (NN - 1), b_ = m >> 11;
                    float v = acc[rt][ct][r] + bv;
                    float2 cs = ((const float2*)tab)[n * 64 + d];
                    float part = __shfl_xor(v, 1);
                    float vr = (l & 1) ? fmaf(part, cs.y, v * cs.x)
                                       : fmaf(-part, cs.y, v * cs.x);
                    u16* qp = (u16*)out + (((size_t)b_ * NH + h) * NN + n) * HD + d;
                    *qp = f2b(vr * scl);
                }
        }
    }
}

__global__ __launch_bounds__(256)
void qkv_k(const u16* __restrict__ X,
           const u16* __restrict__ Wq, const u16* __restrict__ Wk, const u16* __restrict__ Wv,
           const float* __restrict__ bq, const float* __restrict__ bk, const float* __restrict__ bv,
           u16* __restrict__ qo, u16* __restrict__ ko, u16* __restrict__ vo,
           const float* __restrict__ tab) {
    int z = blockIdx.z;
    const u16* W   = (z == 0) ? Wq : (z == 1) ? Wk : Wv;
    const float* b = (z == 0) ? bq : (z == 1) ? bk : bv;
    u16* o         = (z == 0) ? qo : (z == 1) ? ko : vo;
    gemm_body(X, W, b, o, tab, z);
}

__global__ __launch_bounds__(256)
void projo_k(const u16* __restrict__ X, const u16* __restrict__ W,
             const float* __restrict__ b, float* __restrict__ out) {
    gemm_body(X, W, b, out, nullptr, 3);
}

// ---------------------------------------------------------------------------
// MFMA flash attention.
//  - Q frags hoisted to registers; P buffer aliases Q's LDS (40KB -> 4 blk/CU)
//  - lazy max: partial per-lane max + __any gate; full reduce+rescale rare
//  - row-sum l via ones-MFMA (no sum shuffles)
//  - double-buffered K/V, 1 barrier/iter, setprio, XCD swizzle
// ---------------------------------------------------------------------------
__global__ __launch_bounds__(256)
void attn_mfma_k(const u16* __restrict__ Qb, const u16* __restrict__ Kb,
                 const u16* __restrict__ Vtb, u16* __restrict__ ctxb) {
    __shared__ u16 QPs[64 * 64];          // Q staging, then P
    __shared__ u16 Ks[2][64 * 64];
    __shared__ u16 Vs[2][64 * 64];

    const int t = threadIdx.x, w = t >> 6, l = t & 63;
    // XCD swizzle: all 32 q-tiles of one bh on one XCD -> K/V L2-resident
    int f   = blockIdx.y * 32 + blockIdx.x;
    int bh  = (f & 7) * 4 + ((f >> 3) & 3);
    int qt  = f >> 5;
    const int b_ = bh >> 4, h = bh & 15;

    const u16* Qg  = Qb + ((size_t)bh * NN + qt * 64) * HD;
    const u16* Kg0 = Kb + (size_t)bh * NN * HD;
    const u16* Vg0 = Vtb + (size_t)bh * HD * NN;

    const int ch0 = (w << 6) + l;
    const int r0 = ch0 >> 3,         s0 = (ch0 & 7) ^ (r0 & 7);
    const int r1 = (ch0 + 256) >> 3, s1 = (ch0 & 7) ^ (r1 & 7);

    gload16(QPs + ((w << 6)) * 8,       Qg + r0 * HD + s0 * 8);
    gload16(QPs + (256 + (w << 6)) * 8, Qg + r1 * HD + s1 * 8);
    gload16(Ks[0] + ((w << 6)) * 8,       Kg0 + (size_t)r0 * HD + s0 * 8);
    gload16(Ks[0] + (256 + (w << 6)) * 8, Kg0 + (size_t)r1 * HD + s1 * 8);
    gload16(Vs[0] + ((w << 6)) * 8,       Vg0 + (size_t)r0 * NN + s0 * 8);
    gload16(Vs[0] + (256 + (w << 6)) * 8, Vg0 + (size_t)r1 * NN + s1 * 8);
    __syncthreads();

    // hoist Q fragments (loop-invariant)
    bf16x8 qf[2];
#pragma unroll
    for (int kk = 0; kk < 2; ++kk) {
        int row = w * 16 + (l & 15);
        int cb = (kk * 64 + (l >> 4) * 16) ^ ((row & 7) << 4);
        qf[kk] = *(const bf16x8*)((const char*)QPs + row * 128 + cb);
    }
    __syncthreads();    // all qf reads done before QPs is reused for P

    bf16x8 ones;
#pragma unroll
    for (int i = 0; i < 8; ++i) ones[i] = (short)0x3F80;   // bf16 1.0

    float m_i[4] = {-INFINITY, -INFINITY, -INFINITY, -INFINITY};
    float l_i[4] = {};
    f32x4 o_acc[4] = {};

    int cur = 0;
    for (int kt = 0; kt < NN / 64; ++kt, cur ^= 1) {
        if (kt + 1 < NN / 64) {
            const u16* Kg = Kg0 + (size_t)((kt + 1) * 64) * HD;
            const u16* Vg = Vg0 + (kt + 1) * 64;
            gload16(Ks[cur ^ 1] + ((w << 6)) * 8,       Kg + (size_t)r0 * HD + s0 * 8);
            gload16(Ks[cur ^ 1] + (256 + (w << 6)) * 8, Kg + (size_t)r1 * HD + s1 * 8);
            gload16(Vs[cur ^ 1] + ((w << 6)) * 8,       Vg + (size_t)r0 * NN + s0 * 8);
            gload16(Vs[cur ^ 1] + (256 + (w << 6)) * 8, Vg + (size_t)r1 * NN + s1 * 8);
        }

        // ---- S = Q K^T (log2 domain) ----
        f32x4 sacc[4] = {};
        __builtin_amdgcn_s_setprio(1);
#pragma unroll
        for (int ct = 0; ct < 4; ++ct)
#pragma unroll
            for (int kk = 0; kk < 2; ++kk) {
                int row = ct * 16 + (l & 15);
                int cb = (kk * 64 + (l >> 4) * 16) ^ ((row & 7) << 4);
                bf16x8 kf = *(const bf16x8*)((const char*)Ks[cur] + row * 128 + cb);
                sacc[ct] = __builtin_amdgcn_mfma_f32_16x16x32_bf16(qf[kk], kf, sacc[ct], 0, 0, 0);
            }
        __builtin_amdgcn_s_setprio(0);

        // ---- lazy max: per-lane partials, gate the full reduce ----
        float pm[4];
#pragma unroll
        for (int r = 0; r < 4; ++r)
            pm[r] = fmaxf(fmaxf(sacc[0][r], sacc[1][r]), fmaxf(sacc[2][r], sacc[3][r]));
        bool grow = (pm[0] > m_i[0] + DTHR) | (pm[1] > m_i[1] + DTHR) |
                    (pm[2] > m_i[2] + DTHR) | (pm[3] > m_i[3] + DTHR);
        if (__any(grow)) {                 // tile 0, then rare
#pragma unroll
            for (int r = 0; r < 4; ++r) {
                float mx = pm[r];
                mx = fmaxf(mx, __shfl_xor(mx, 1));
                mx = fmaxf(mx, __shfl_xor(mx, 2));
                mx = fmaxf(mx, __shfl_xor(mx, 4));
                mx = fmaxf(mx, __shfl_xor(mx, 8));
                float mn = fmaxf(m_i[r], mx);
                float alpha = __builtin_amdgcn_exp2f(m_i[r] - mn);
                m_i[r] = mn;
                l_i[r] *= alpha;
#pragma unroll
                for (int dt = 0; dt < 4; ++dt) o_acc[dt][r] *= alpha;
            }
        }

        // ---- P = exp2(S - m), store bf16 swizzled (wave-private rows) ----
#pragma unroll
        for (int ct = 0; ct < 4; ++ct)
#pragma unroll
            for (int r = 0; r < 4; ++r) {
                float p = __builtin_amdgcn_exp2f(sacc[ct][r] - m_i[r]);
                int row = w * 16 + (l >> 4) * 4 + r;
                int cb = ((ct * 16 + (l & 15)) * 2) ^ ((row & 7) << 4);
                *(u16*)((char*)QPs + row * 128 + cb) = f2bc(p);
            }

        // ---- O += P V ; l += P·1 (ones-MFMA row sums) ----
        f32x4 lacc = {};
        __builtin_amdgcn_s_setprio(1);
#pragma unroll
        for (int kk = 0; kk < 2; ++kk) {
            int prow = w * 16 + (l & 15);
            int pcb = (kk * 64 + (l >> 4) * 16) ^ ((prow & 7) << 4);
            bf16x8 pf = *(const bf16x8*)((const char*)QPs + prow * 128 + pcb);
            lacc = __builtin_amdgcn_mfma_f32_16x16x32_bf16(pf, ones, lacc, 0, 0, 0);
#pragma unroll
            for (int dt = 0; dt < 4; ++dt) {
                int vrow = dt * 16 + (l & 15);
                int vcb = (kk * 64 + (l >> 4) * 16) ^ ((vrow & 7) << 4);
                bf16x8 vf = *(const bf16x8*)((const char*)Vs[cur] + vrow * 128 + vcb);
                o_acc[dt] = __builtin_amdgcn_mfma_f32_16x16x32_bf16(pf, vf, o_acc[dt], 0, 0, 0);
            }
        }
        __builtin_amdgcn_s_setprio(0);
#pragma unroll
        for (int r = 0; r < 4; ++r) l_i[r] += lacc[r];

        __syncthreads();   // waves done with cur; prefetch (into cur^1) drained
    }

    // ---- normalize + write ctx bf16 [b][n][h*64+d] ----
#pragma unroll
    for (int r = 0; r < 4; ++r) {
        float inv = 1.f / l_i[r];
        int n = qt * 64 + w * 16 + (l >> 4) * 4 + r;
#pragma unroll
        for (int dt = 0; dt < 4; ++dt) {
            int d = dt * 16 + (l & 15);
            ctxb[((size_t)b_ * NN + n) * HSZ + h * HD + d] = f2bc(o_acc[dt][r] * inv);
        }
    }
}

// ---------------------------------------------------------------------------
extern "C" void kernel_launch(void* const* d_in, const int* in_sizes, int n_in,
                              void* d_out, int out_size, void* d_ws, size_t ws_size,
                              hipStream_t stream) {
    (void)in_sizes; (void)n_in; (void)out_size; (void)ws_size;
    const float* hs = (const float*)d_in[0];
    const float* Wq = (const float*)d_in[1];
    const float* bq = (const float*)d_in[2];
    const float* Wk = (const float*)d_in[3];
    const float* bk = (const float*)d_in[4];
    const float* Wv = (const float*)d_in[5];
    const float* bv = (const float*)d_in[6];
    const float* Wp = (const float*)d_in[7];
    const float* bp = (const float*)d_in[8];

    char* ws = (char*)d_ws;
    u16*   hsb  = (u16*)(ws);
    u16*   Wqb  = (u16*)(ws + 8388608);
    u16*   Wkb  = (u16*)(ws + 10485760);
    u16*   Wvb  = (u16*)(ws + 12582912);
    u16*   Wpb  = (u16*)(ws + 14680064);
    u16*   qb   = (u16*)(ws + 16777216);
    u16*   kb   = (u16*)(ws + 25165824);
    u16*   vtb  = (u16*)(ws + 33554432);
    u16*   ctxb = (u16*)(ws + 41943040);
    float* tab  = (float*)(ws + 50331648);

    cast_k<<<8192, 256, 0, stream>>>(hs, Wq, Wk, Wv, Wp, hsb, Wqb, Wkb, Wvb, Wpb);
    rope_table_k<<<NN, 64, 0, stream>>>(tab);

    qkv_k<<<dim3(HSZ / 64, (BB * NN) / 128, 3), 256, 0, stream>>>(
        hsb, Wqb, Wkb, Wvb, bq, bk, bv, qb, kb, vtb, tab);

    attn_mfma_k<<<dim3(NN / 64, BB * NH), 256, 0, stream>>>(qb, kb, vtb, ctxb);

    projo_k<<<dim3(HSZ / 64, (BB * NN) / 128), 256, 0, stream>>>(ctxb, Wpb, bp, (float*)d_out);
}

// Round 5
// 150.914 us; speedup vs baseline: 8.0580x; 1.0580x over previous
//
#include <hip/hip_runtime.h>
#include <hip/hip_bf16.h>
#include <math.h>

#define BB    2
#define NN    2048
#define HSZ   1024
#define NH    16
#define HD    64
#define SEGW  20

#define LOG2E  1.4426950408889634f
#define QSCALE (0.125f * LOG2E)     // folded into Q at projection time
#define DTHR   8.0f                 // defer-max threshold (log2 units)

typedef unsigned short u16;
typedef unsigned int   u32;
using bf16x8 = __attribute__((ext_vector_type(8))) short;
using f32x4  = __attribute__((ext_vector_type(4))) float;

// float -> bf16 (RNE), manual
__device__ __forceinline__ u16 f2b(float f) {
    union { float f; u32 u; } x; x.f = f;
    u32 r = x.u + 0x7FFF + ((x.u >> 16) & 1);
    return (u16)(r >> 16);
}
// float -> bf16 via compiler cvt (hot path)
__device__ __forceinline__ u16 f2bc(float f) {
    __hip_bfloat16 h = __float2bfloat16(f);
    return *reinterpret_cast<u16*>(&h);
}

// async global->LDS, 16B/lane; lds base wave-uniform
__device__ __forceinline__ void gload16(void* lds, const void* g) {
    __builtin_amdgcn_global_load_lds(
        (const __attribute__((address_space(1))) void*)g,
        (__attribute__((address_space(3))) void*)lds, 16, 0, 0);
}

// ---------------------------------------------------------------------------
__global__ __launch_bounds__(256)
void cast_k(const float* __restrict__ hs, const float* __restrict__ Wq,
            const float* __restrict__ Wk, const float* __restrict__ Wv,
            const float* __restrict__ Wp, u16* __restrict__ hsb,
            u16* __restrict__ wqb, u16* __restrict__ wkb,
            u16* __restrict__ wvb, u16* __restrict__ wpb) {
    size_t idx = ((size_t)blockIdx.x * 256 + threadIdx.x) * 4;
    const float* s; u16* d; size_t o;
    const size_t HSN = 4194304, WN = 1048576;
    if      (idx < HSN)          { s = hs; d = hsb; o = idx; }
    else if (idx < HSN + WN)     { s = Wq; d = wqb; o = idx - HSN; }
    else if (idx < HSN + 2*WN)   { s = Wk; d = wkb; o = idx - HSN - WN; }
    else if (idx < HSN + 3*WN)   { s = Wv; d = wvb; o = idx - HSN - 2*WN; }
    else                         { s = Wp; d = wpb; o = idx - HSN - 3*WN; }
    float4 v = *(const float4*)(s + o);
    u32 lo = f2b(v.x) | ((u32)f2b(v.y) << 16);
    u32 hi = f2b(v.z) | ((u32)f2b(v.w) << 16);
    *(uint2*)(d + o) = uint2{lo, hi};
}

// ---------------------------------------------------------------------------
__global__ void rope_table_k(float* __restrict__ tab) {
    int n = blockIdx.x, d = threadIdx.x;
    float c = 1.f, s = 0.f;
    if (d < 3 * SEGW) {
        int seg = d / SEGW;
        int jj  = (d % SEGW) % (SEGW / 2);
        int rem = n & 255;
        int pos = (seg == 0) ? (n >> 8) : ((seg == 1) ? (rem >> 4) : (rem & 15));
        float omega = powf(10000.f, -(float)jj / 10.f);
        float fr = (float)pos * omega;
        s = sinf(fr); c = cosf(fr);
    }
    tab[(n * 64 + d) * 2 + 0] = c;
    tab[(n * 64 + d) * 2 + 1] = s;
}

// ---------------------------------------------------------------------------
// m97-style GEMM: C[m,o] = sum_k X[m,k]*W[o,k] + bias[o]
// BM=BN=128, BK=32, 4 waves (2x2 of 64x64), dbuf, 1 barrier/iter.
// Staging source pre-swizzled by (c&3)^(row&3) -> frag-read 8-way -> 4-way.
// mode 0: rope+QSCALE bf16 [bh][n][d]; 1: rope bf16 [bh][n][d];
// mode 2: bf16 [bh][d][n] (V transposed); 3: fp32 [m][o].
// ---------------------------------------------------------------------------
__device__ __forceinline__
void gemm_body(const u16* __restrict__ X, const u16* __restrict__ Wb,
               const float* __restrict__ bias, void* __restrict__ out,
               const float* __restrict__ tab, int mode) {
    __shared__ u16 As[2][128 * 32];
    __shared__ u16 Bs[2][128 * 32];

    const int t  = threadIdx.x;
    const int w  = t >> 6;
    const int l  = t & 63;
    const int o0 = blockIdx.x * 128;
    const int m0 = blockIdx.y * 128;
    const int wr = (w >> 1) * 64;
    const int wc = (w & 1) * 64;

    // staging: 512 chunks of 16B per buffer; chunk c -> row c>>2, swizzled col
    const int ch  = (w << 6) + l;
    const int rA0 = ch >> 2,         cA0 = (((ch & 3) ^ (rA0 & 3))) * 8;
    const int rA1 = (ch + 256) >> 2, cA1 = (((ch & 3) ^ (rA1 & 3))) * 8;
    // fragment read byte-col (same for A and B since row&3 == l&3)
    const int kbyte = (((l >> 4) ^ (l & 3)) << 4);

    f32x4 acc[4][4] = {};

    gload16(As[0] + ((w << 6)) * 8,       X  + (size_t)(m0 + rA0) * HSZ + cA0);
    gload16(As[0] + (256 + (w << 6)) * 8, X  + (size_t)(m0 + rA1) * HSZ + cA1);
    gload16(Bs[0] + ((w << 6)) * 8,       Wb + (size_t)(o0 + rA0) * HSZ + cA0);
    gload16(Bs[0] + (256 + (w << 6)) * 8, Wb + (size_t)(o0 + rA1) * HSZ + cA1);
    __syncthreads();

    int cur = 0;
    for (int k0 = 0; k0 < HSZ; k0 += 32, cur ^= 1) {
        if (k0 + 32 < HSZ) {
            int kn = k0 + 32;
            gload16(As[cur ^ 1] + ((w << 6)) * 8,       X  + (size_t)(m0 + rA0) * HSZ + kn + cA0);
            gload16(As[cur ^ 1] + (256 + (w << 6)) * 8, X  + (size_t)(m0 + rA1) * HSZ + kn + cA1);
            gload16(Bs[cur ^ 1] + ((w << 6)) * 8,       Wb + (size_t)(o0 + rA0) * HSZ + kn + cA0);
            gload16(Bs[cur ^ 1] + (256 + (w << 6)) * 8, Wb + (size_t)(o0 + rA1) * HSZ + kn + cA1);
        }
        bf16x8 af[4], bfr[4];
#pragma unroll
        for (int i = 0; i < 4; ++i) {
            int row = wr + i * 16 + (l & 15);
            af[i] = *(const bf16x8*)((const char*)As[cur] + row * 64 + kbyte);
        }
#pragma unroll
        for (int j = 0; j < 4; ++j) {
            int row = wc + j * 16 + (l & 15);
            bfr[j] = *(const bf16x8*)((const char*)Bs[cur] + row * 64 + kbyte);
        }
        __builtin_amdgcn_s_setprio(1);
#pragma unroll
        for (int i = 0; i < 4; ++i)
#pragma unroll
            for (int j = 0; j < 4; ++j)
                acc[i][j] = __builtin_amdgcn_mfma_f32_16x16x32_bf16(af[i], bfr[j], acc[i][j], 0, 0, 0);
        __builtin_amdgcn_s_setprio(0);
        __syncthreads();
    }

    // ---- epilogue ----
#pragma unroll
    for (int j = 0; j < 4; ++j) {
        int oc = o0 + wc + j * 16 + (l & 15);
        int h  = oc >> 6;
        int d  = oc & 63;
        float bv = bias[oc];
        if (mode == 2) {
#pragma unroll
            for (int rt = 0; rt < 4; ++rt) {
                int base = m0 + wr + rt * 16 + (l >> 4) * 4;
                int b_ = base >> 11, n0 = base & (NN - 1);
                u16 e[4];
#pragma unroll
                for (int r = 0; r < 4; ++r) e[r] = f2b(acc[rt][j][r] + bv);
                u32 lo = e[0] | ((u32)e[1] << 16);
                u32 hi = e[2] | ((u32)e[3] << 16);
                u16* vp = (u16*)out + (((size_t)b_ * NH + h) * HD + d) * NN + n0;
                *(uint2*)vp = uint2{lo, hi};
            }
        } else if (mode == 3) {
#pragma unroll
            for (int rt = 0; rt < 4; ++rt)
#pragma unroll
                for (int r = 0; r < 4; ++r) {
                    int m = m0 + wr + rt * 16 + (l >> 4) * 4 + r;
                    ((float*)out)[(size_t)m * HSZ + oc] = acc[rt][j][r] + bv;
                }
        } else {
            float scl = (mode == 0) ? QSCALE : 1.f;
#pragma unroll
            for (int rt = 0; rt < 4; ++rt)
#pragma unroll
                for (int r = 0; r < 4; ++r) {
                    int m = m0 + wr + rt * 16 + (l >> 4) * 4 + r;
                    int n = m & (NN - 1), b_ = m >> 11;
                    float v = acc[rt][j][r] + bv;
                    float2 cs = ((const float2*)tab)[n * 64 + d];
                    float part = __shfl_xor(v, 1);
                    float vr = (l & 1) ? fmaf(part, cs.y, v * cs.x)
                                       : fmaf(-part, cs.y, v * cs.x);
                    u16* qp = (u16*)out + (((size_t)b_ * NH + h) * NN + n) * HD + d;
                    *qp = f2b(vr * scl);
                }
        }
    }
}

__global__ __launch_bounds__(256)
void qkv_k(const u16* __restrict__ X,
           const u16* __restrict__ Wq, const u16* __restrict__ Wk, const u16* __restrict__ Wv,
           const float* __restrict__ bq, const float* __restrict__ bk, const float* __restrict__ bv,
           u16* __restrict__ qo, u16* __restrict__ ko, u16* __restrict__ vo,
           const float* __restrict__ tab) {
    int z = blockIdx.z;
    const u16* W   = (z == 0) ? Wq : (z == 1) ? Wk : Wv;
    const float* b = (z == 0) ? bq : (z == 1) ? bk : bv;
    u16* o         = (z == 0) ? qo : (z == 1) ? ko : vo;
    gemm_body(X, W, b, o, tab, z);
}

__global__ __launch_bounds__(256)
void projo_k(const u16* __restrict__ X, const u16* __restrict__ W,
             const float* __restrict__ b, float* __restrict__ out) {
    gemm_body(X, W, b, out, nullptr, 3);
}

// ---------------------------------------------------------------------------
// MFMA flash attention, QBLK=128: 4 waves x 32 q-rows each -> K/V LDS reads
// amortized 2x. K/V dbuf, 1 barrier/iter, lazy-max, ones-MFMA row sums,
// setprio, XCD swizzle. LDS 48KB. Q pre-scaled by 0.125*log2e.
// ---------------------------------------------------------------------------
__global__ __launch_bounds__(256)
void attn_mfma_k(const u16* __restrict__ Qb, const u16* __restrict__ Kb,
                 const u16* __restrict__ Vtb, u16* __restrict__ ctxb) {
    __shared__ u16 QPs[128 * 64];     // 16KB: Q staging, then P (wave-private rows)
    __shared__ u16 Ks[2][64 * 64];    // 16KB
    __shared__ u16 Vs[2][64 * 64];    // 16KB

    const int t = threadIdx.x, w = t >> 6, l = t & 63;
    // XCD swizzle: 16 q-tiles of one bh on one XCD -> K/V L2-resident
    int f  = blockIdx.y * 16 + blockIdx.x;        // 0..511
    int bh = (f & 7) * 4 + ((f >> 3) & 3);
    int qt = f >> 5;                              // 0..15
    const int b_ = bh >> 4, h = bh & 15;

    const u16* Qg  = Qb + ((size_t)bh * NN + qt * 128) * HD;
    const u16* Kg0 = Kb + (size_t)bh * NN * HD;
    const u16* Vg0 = Vtb + (size_t)bh * HD * NN;

    const int ch0 = (w << 6) + l;
    const int r0 = ch0 >> 3,         s0 = (ch0 & 7) ^ (r0 & 7);
    const int r1 = (ch0 + 256) >> 3, s1 = (ch0 & 7) ^ (r1 & 7);

    // stage Q (128 rows = 4 issues) + K/V tile 0
#pragma unroll
    for (int s = 0; s < 4; ++s) {
        int c = s * 256 + ch0;
        int row = c >> 3, sc = (c & 7) ^ (row & 7);
        gload16(QPs + (s * 256 + (w << 6)) * 8, Qg + row * HD + sc * 8);
    }
    gload16(Ks[0] + ((w << 6)) * 8,       Kg0 + (size_t)r0 * HD + s0 * 8);
    gload16(Ks[0] + (256 + (w << 6)) * 8, Kg0 + (size_t)r1 * HD + s1 * 8);
    gload16(Vs[0] + ((w << 6)) * 8,       Vg0 + (size_t)r0 * NN + s0 * 8);
    gload16(Vs[0] + (256 + (w << 6)) * 8, Vg0 + (size_t)r1 * NN + s1 * 8);
    __syncthreads();

    // hoist Q fragments: 2 q-subtiles x 2 k-halves
    bf16x8 qf[2][2];
#pragma unroll
    for (int qs = 0; qs < 2; ++qs)
#pragma unroll
        for (int kk = 0; kk < 2; ++kk) {
            int row = w * 32 + qs * 16 + (l & 15);
            int cb = (kk * 64 + (l >> 4) * 16) ^ ((row & 7) << 4);
            qf[qs][kk] = *(const bf16x8*)((const char*)QPs + row * 128 + cb);
        }
    __syncthreads();    // qf reads done before QPs is reused for P

    bf16x8 ones;
#pragma unroll
    for (int i = 0; i < 8; ++i) ones[i] = (short)0x3F80;

    float m_i[2][4], l_i[2][4] = {};
#pragma unroll
    for (int qs = 0; qs < 2; ++qs)
#pragma unroll
        for (int r = 0; r < 4; ++r) m_i[qs][r] = -INFINITY;
    f32x4 o_acc[2][4] = {};

    int cur = 0;
    for (int kt = 0; kt < NN / 64; ++kt, cur ^= 1) {
        if (kt + 1 < NN / 64) {
            const u16* Kg = Kg0 + (size_t)((kt + 1) * 64) * HD;
            const u16* Vg = Vg0 + (kt + 1) * 64;
            gload16(Ks[cur ^ 1] + ((w << 6)) * 8,       Kg + (size_t)r0 * HD + s0 * 8);
            gload16(Ks[cur ^ 1] + (256 + (w << 6)) * 8, Kg + (size_t)r1 * HD + s1 * 8);
            gload16(Vs[cur ^ 1] + ((w << 6)) * 8,       Vg + (size_t)r0 * NN + s0 * 8);
            gload16(Vs[cur ^ 1] + (256 + (w << 6)) * 8, Vg + (size_t)r1 * NN + s1 * 8);
        }

        // ---- S = Q K^T: kf read once, used by both q-subtiles ----
        f32x4 sacc[2][4] = {};
        __builtin_amdgcn_s_setprio(1);
#pragma unroll
        for (int ct = 0; ct < 4; ++ct) {
            int row = ct * 16 + (l & 15);
#pragma unroll
            for (int kk = 0; kk < 2; ++kk) {
                int cb = (kk * 64 + (l >> 4) * 16) ^ ((row & 7) << 4);
                bf16x8 kf = *(const bf16x8*)((const char*)Ks[cur] + row * 128 + cb);
                sacc[0][ct] = __builtin_amdgcn_mfma_f32_16x16x32_bf16(qf[0][kk], kf, sacc[0][ct], 0, 0, 0);
                sacc[1][ct] = __builtin_amdgcn_mfma_f32_16x16x32_bf16(qf[1][kk], kf, sacc[1][ct], 0, 0, 0);
            }
        }
        __builtin_amdgcn_s_setprio(0);

        // ---- lazy max ----
        float pm[2][4];
        bool grow = false;
#pragma unroll
        for (int qs = 0; qs < 2; ++qs)
#pragma unroll
            for (int r = 0; r < 4; ++r) {
                pm[qs][r] = fmaxf(fmaxf(sacc[qs][0][r], sacc[qs][1][r]),
                                  fmaxf(sacc[qs][2][r], sacc[qs][3][r]));
                grow = grow | (pm[qs][r] > m_i[qs][r] + DTHR);
            }
        if (__any(grow)) {                 // tile 0, then rare
#pragma unroll
            for (int qs = 0; qs < 2; ++qs)
#pragma unroll
                for (int r = 0; r < 4; ++r) {
                    float mx = pm[qs][r];
                    mx = fmaxf(mx, __shfl_xor(mx, 1));
                    mx = fmaxf(mx, __shfl_xor(mx, 2));
                    mx = fmaxf(mx, __shfl_xor(mx, 4));
                    mx = fmaxf(mx, __shfl_xor(mx, 8));
                    float mn = fmaxf(m_i[qs][r], mx);
                    float alpha = __builtin_amdgcn_exp2f(m_i[qs][r] - mn);
                    m_i[qs][r] = mn;
                    l_i[qs][r] *= alpha;
#pragma unroll
                    for (int dt = 0; dt < 4; ++dt) o_acc[qs][dt][r] *= alpha;
                }
        }

        // ---- P = exp2(S - m) -> LDS bf16 swizzled (wave-private rows) ----
#pragma unroll
        for (int qs = 0; qs < 2; ++qs)
#pragma unroll
            for (int ct = 0; ct < 4; ++ct)
#pragma unroll
                for (int r = 0; r < 4; ++r) {
                    float p = __builtin_amdgcn_exp2f(sacc[qs][ct][r] - m_i[qs][r]);
                    int row = w * 32 + qs * 16 + (l >> 4) * 4 + r;
                    int cb = ((ct * 16 + (l & 15)) * 2) ^ ((row & 7) << 4);
                    *(u16*)((char*)QPs + row * 128 + cb) = f2bc(p);
                }

        // ---- O += P V ; l += P·1 (vf read once, used by both q-subtiles) ----
        f32x4 lacc[2] = {};
        __builtin_amdgcn_s_setprio(1);
#pragma unroll
        for (int kk = 0; kk < 2; ++kk) {
            bf16x8 pf[2];
#pragma unroll
            for (int qs = 0; qs < 2; ++qs) {
                int prow = w * 32 + qs * 16 + (l & 15);
                int pcb = (kk * 64 + (l >> 4) * 16) ^ ((prow & 7) << 4);
                pf[qs] = *(const bf16x8*)((const char*)QPs + prow * 128 + pcb);
            }
            lacc[0] = __builtin_amdgcn_mfma_f32_16x16x32_bf16(pf[0], ones, lacc[0], 0, 0, 0);
            lacc[1] = __builtin_amdgcn_mfma_f32_16x16x32_bf16(pf[1], ones, lacc[1], 0, 0, 0);
#pragma unroll
            for (int dt = 0; dt < 4; ++dt) {
                int vrow = dt * 16 + (l & 15);
                int vcb = (kk * 64 + (l >> 4) * 16) ^ ((vrow & 7) << 4);
                bf16x8 vf = *(const bf16x8*)((const char*)Vs[cur] + vrow * 128 + vcb);
                o_acc[0][dt] = __builtin_amdgcn_mfma_f32_16x16x32_bf16(pf[0], vf, o_acc[0][dt], 0, 0, 0);
                o_acc[1][dt] = __builtin_amdgcn_mfma_f32_16x16x32_bf16(pf[1], vf, o_acc[1][dt], 0, 0, 0);
            }
        }
        __builtin_amdgcn_s_setprio(0);
#pragma unroll
        for (int qs = 0; qs < 2; ++qs)
#pragma unroll
            for (int r = 0; r < 4; ++r) l_i[qs][r] += lacc[qs][r];

        __syncthreads();   // waves done with cur; prefetch (into cur^1) drained
    }

    // ---- normalize + write ctx bf16 [b][n][h*64+d] ----
#pragma unroll
    for (int qs = 0; qs < 2; ++qs)
#pragma unroll
        for (int r = 0; r < 4; ++r) {
            float inv = 1.f / l_i[qs][r];
            int n = qt * 128 + w * 32 + qs * 16 + (l >> 4) * 4 + r;
#pragma unroll
            for (int dt = 0; dt < 4; ++dt) {
                int d = dt * 16 + (l & 15);
                ctxb[((size_t)b_ * NN + n) * HSZ + h * HD + d] = f2bc(o_acc[qs][dt][r] * inv);
            }
        }
}

// ---------------------------------------------------------------------------
extern "C" void kernel_launch(void* const* d_in, const int* in_sizes, int n_in,
                              void* d_out, int out_size, void* d_ws, size_t ws_size,
                              hipStream_t stream) {
    (void)in_sizes; (void)n_in; (void)out_size; (void)ws_size;
    const float* hs = (const float*)d_in[0];
    const float* Wq = (const float*)d_in[1];
    const float* bq = (const float*)d_in[2];
    const float* Wk = (const float*)d_in[3];
    const float* bk = (const float*)d_in[4];
    const float* Wv = (const float*)d_in[5];
    const float* bv = (const float*)d_in[6];
    const float* Wp = (const float*)d_in[7];
    const float* bp = (const float*)d_in[8];

    char* ws = (char*)d_ws;
    u16*   hsb  = (u16*)(ws);
    u16*   Wqb  = (u16*)(ws + 8388608);
    u16*   Wkb  = (u16*)(ws + 10485760);
    u16*   Wvb  = (u16*)(ws + 12582912);
    u16*   Wpb  = (u16*)(ws + 14680064);
    u16*   qb   = (u16*)(ws + 16777216);
    u16*   kb   = (u16*)(ws + 25165824);
    u16*   vtb  = (u16*)(ws + 33554432);
    u16*   ctxb = (u16*)(ws + 41943040);
    float* tab  = (float*)(ws + 50331648);

    cast_k<<<8192, 256, 0, stream>>>(hs, Wq, Wk, Wv, Wp, hsb, Wqb, Wkb, Wvb, Wpb);
    rope_table_k<<<NN, 64, 0, stream>>>(tab);

    qkv_k<<<dim3(HSZ / 128, (BB * NN) / 128, 3), 256, 0, stream>>>(
        hsb, Wqb, Wkb, Wvb, bq, bk, bv, qb, kb, vtb, tab);

    attn_mfma_k<<<dim3(NN / 128, BB * NH), 256, 0, stream>>>(qb, kb, vtb, ctxb);

    projo_k<<<dim3(HSZ / 128, (BB * NN) / 128), 256, 0, stream>>>(ctxb, Wpb, bp, (float*)d_out);
}